// Round 5
// baseline (317.715 us; speedup 1.0000x reference)
//
#include <hip/hip_runtime.h>

#define NB 65536
#define NATOM 256
#define NA 64
#define NM 128
#define TRAJ_SZ (NB*NATOM*3)   // 50331648
#define REF_SZ  (NATOM*3)      // 768
#define SLOT_F  384            // floats per batch output slot (1536 bytes)
#define ROW_F   (NATOM*3)      // 768 floats (3072 B) per batch traj row
#define NBB     8              // batches per block (256 threads, 4 waves)

__device__ __forceinline__ float bf2f(unsigned short u) {
    union { unsigned int i; float f; } v; v.i = ((unsigned int)u) << 16; return v.f;
}
// expand a dword holding two bf16 into two floats (2 VALU)
__device__ __forceinline__ float2 bf2x2(unsigned int u) {
    union { unsigned int i; float f; } lo, hi;
    lo.i = u << 16; hi.i = u & 0xffff0000u;
    return make_float2(lo.f, hi.f);
}

// ---- DPP wave reduction (VALU-only; no DS-pipe traffic) ----
// gfx9 pattern (rocPRIM): row_shr 1/2/4/8 then row_bcast15/31.
// bound_ctrl=true -> invalid source lanes yield 0. Full sum valid in lane 63.
template<int CTRL>
__device__ __forceinline__ float dpp_add(float x) {
    int m = __builtin_amdgcn_update_dpp(0, __float_as_int(x), CTRL, 0xf, 0xf, true);
    return x + __int_as_float(m);
}
__device__ __forceinline__ float wave_sum63(float x) {
    x = dpp_add<0x111>(x);   // row_shr:1
    x = dpp_add<0x112>(x);   // row_shr:2
    x = dpp_add<0x114>(x);   // row_shr:4
    x = dpp_add<0x118>(x);   // row_shr:8
    x = dpp_add<0x142>(x);   // row_bcast:15
    x = dpp_add<0x143>(x);   // row_bcast:31
    return x;                // total in lane 63
}
__device__ __forceinline__ float wave_sum_bcast(float x) {
    return __int_as_float(__builtin_amdgcn_readlane(__float_as_int(wave_sum63(x)), 63));
}
template<int CTRL>
__device__ __forceinline__ float dpp_max(float x) {
    int m = __builtin_amdgcn_update_dpp(0, __float_as_int(x), CTRL, 0xf, 0xf, true);
    return fmaxf(x, __int_as_float(m));
}
__device__ __forceinline__ float wave_max_bcast(float x) {   // x >= 0 assumed
    x = dpp_max<0x111>(x);
    x = dpp_max<0x112>(x);
    x = dpp_max<0x114>(x);
    x = dpp_max<0x118>(x);
    x = dpp_max<0x142>(x);
    x = dpp_max<0x143>(x);
    return __int_as_float(__builtin_amdgcn_readlane(__float_as_int(x), 63));
}

// Fused, 8 batches/block:
//  0. issue 3 raw dwordx4 loads (bf16-layout addresses) immediately
//  1. dtype probe on the LOADED registers (no extra global read):
//       bf16 storage          -> low-half-viewed bf16 max in ~[2,6]  -> 0
//       f32 full precision    -> random exponent bits: huge max      -> 1
//       f32 w/ bf16-ed values -> low mantissa halves zero: max == 0  -> 1
//     expand/stage into LDS (f32 path re-issues 6 dwordx4 at f32 addresses)
//  2. wave w computes P + xc for batches 2w, 2w+1 via DPP reductions
//  3. threads 0..7 each run ONE batch's 3x3 Kabsch (SVD amortized 8x)
//  4. wave w applies rot for batches 2w, 2w+1 and stores DIRECTLY to global
//     (per-batch output slot is contiguous: per-lane 12 B stores coalesce)
__global__ __launch_bounds__(256) void k_fused(const unsigned short* __restrict__ traj_u,
                                               const unsigned short* __restrict__ refp_u,
                                               const int* __restrict__ align_idx,
                                               const int* __restrict__ nn_idx,
                                               float* __restrict__ out) {
    __shared__ float rowbuf[NBB][ROW_F];   // 24 KiB
    __shared__ float pbuf[NBB][12];        // P (9) + xc (3) per batch, then rot + xc
    int tid  = threadIdx.x;
    int lane = tid & 63;
    int wid  = tid >> 6;
    long bbase = (long)blockIdx.x * NBB;

    // ---- 0. raw loads first (bf16-sized region), latency hidden under detect ----
    const uint4* srcb = (const uint4*)(traj_u + bbase * ROW_F);  // 8 rows * 1536 B
    uint4 q0 = srcb[tid];
    uint4 q1 = srcb[tid + 256];
    uint4 q2 = srcb[tid + 512];

    // ---- 1. dtype probe on loaded data ----
    float mx =             fabsf(bf2f((unsigned short)(q0.x & 0xffffu)));
    mx = fmaxf(mx, fabsf(bf2f((unsigned short)(q0.y & 0xffffu))));
    mx = fmaxf(mx, fabsf(bf2f((unsigned short)(q0.z & 0xffffu))));
    mx = fmaxf(mx, fabsf(bf2f((unsigned short)(q0.w & 0xffffu))));
    mx = wave_max_bcast(mx);
    int isf32 = (mx > 0.5f && mx < 100.f) ? 0 : 1;

    if (isf32) {
        // f32 rows are 3072 B: reload 6 dwordx4 from the f32 addresses
        const float4* srcf = (const float4*)((const float*)traj_u + bbase * ROW_F);
        float4* dst = (float4*)&rowbuf[0][0];
        #pragma unroll
        for (int k = 0; k < 6; ++k) dst[tid + 256*k] = srcf[tid + 256*k];
    } else {
        // expand: uint4 j covers bf16 elems 8j..8j+7 -> float4[2j], float4[2j+1]
        float4* dst = (float4*)&rowbuf[0][0];
        uint4 q[3] = {q0, q1, q2};
        #pragma unroll
        for (int k = 0; k < 3; ++k) {
            int j = tid + 256*k;
            float2 a = bf2x2(q[k].x), b = bf2x2(q[k].y);
            float2 c = bf2x2(q[k].z), d = bf2x2(q[k].w);
            dst[2*j]   = make_float4(a.x, a.y, b.x, b.y);
            dst[2*j+1] = make_float4(c.x, c.y, d.x, d.y);
        }
    }
    __syncthreads();

    // ---- 2. P + xc per batch (wave-per-batch, 2 sequential) ----
    int aidx = align_idx[lane];
    float r0, r1, r2;
    if (isf32) {
        const float* rp = (const float*)refp_u;
        r0 = rp[aidx*3+0]; r1 = rp[aidx*3+1]; r2 = rp[aidx*3+2];
    } else {
        r0 = bf2f(refp_u[aidx*3+0]); r1 = bf2f(refp_u[aidx*3+1]); r2 = bf2f(refp_u[aidx*3+2]);
    }
    // center the reference selection (batch-independent, done once)
    r0 -= wave_sum_bcast(r0) * (1.f/64.f);
    r1 -= wave_sum_bcast(r1) * (1.f/64.f);
    r2 -= wave_sum_bcast(r2) * (1.f/64.f);
    #pragma unroll
    for (int s = 0; s < 2; ++s) {
        int lb = 2*wid + s;
        const float* row = rowbuf[lb];
        float x0 = row[aidx*3+0];
        float x1 = row[aidx*3+1];
        float x2 = row[aidx*3+2];
        float p00 = wave_sum63(x0*r0), p01 = wave_sum63(x0*r1), p02 = wave_sum63(x0*r2);
        float p10 = wave_sum63(x1*r0), p11 = wave_sum63(x1*r1), p12 = wave_sum63(x1*r2);
        float p20 = wave_sum63(x2*r0), p21 = wave_sum63(x2*r1), p22 = wave_sum63(x2*r2);
        float xc0 = wave_sum63(x0) * (1.f/64.f);
        float xc1 = wave_sum63(x1) * (1.f/64.f);
        float xc2 = wave_sum63(x2) * (1.f/64.f);
        if (lane == 63) {
            pbuf[lb][0] = p00; pbuf[lb][1] = p01; pbuf[lb][2]  = p02;
            pbuf[lb][3] = p10; pbuf[lb][4] = p11; pbuf[lb][5]  = p12;
            pbuf[lb][6] = p20; pbuf[lb][7] = p21; pbuf[lb][8]  = p22;
            pbuf[lb][9] = xc0; pbuf[lb][10] = xc1; pbuf[lb][11] = xc2;
        }
    }
    __syncthreads();

    // ---- 3. thread-per-batch 3x3 Kabsch (threads 0..7) ----
    if (tid < NBB) {
        float* w = pbuf[tid];
        float p00=w[0], p01=w[1], p02=w[2];
        float p10=w[3], p11=w[4], p12=w[5];
        float p20=w[6], p21=w[7], p22=w[8];
        float s00 = p00*p00 + p10*p10 + p20*p20;
        float s01 = p00*p01 + p10*p11 + p20*p21;
        float s02 = p00*p02 + p10*p12 + p20*p22;
        float s11 = p01*p01 + p11*p11 + p21*p21;
        float s12 = p01*p02 + p11*p12 + p21*p22;
        float s22 = p02*p02 + p12*p12 + p22*p22;
        float v00=1.f,v01=0.f,v02=0.f, v10=0.f,v11=1.f,v12=0.f, v20=0.f,v21=0.f,v22=1.f;
#define JROT(SPP,SQQ,SPQ,SRP,SRQ,VA,VB,VC,VD,VE,VF) { \
        float apq = SPQ; \
        if (apq != 0.0f) { \
            float tau = (SQQ - SPP) / (2.0f*apq); \
            float t = (tau >= 0.0f ? 1.0f : -1.0f) / (fabsf(tau) + sqrtf(1.0f + tau*tau)); \
            float c = 1.0f / sqrtf(1.0f + t*t); \
            float sn = t*c; \
            SPP -= t*apq; SQQ += t*apq; SPQ = 0.0f; \
            float tp = SRP; SRP = c*tp - sn*SRQ; SRQ = sn*tp + c*SRQ; \
            tp = VA; VA = c*tp - sn*VB; VB = sn*tp + c*VB; \
            tp = VC; VC = c*tp - sn*VD; VD = sn*tp + c*VD; \
            tp = VE; VE = c*tp - sn*VF; VF = sn*tp + c*VF; \
        } }
        #pragma unroll
        for (int sweep = 0; sweep < 5; ++sweep) {
            JROT(s00,s11,s01, s02,s12, v00,v01, v10,v11, v20,v21);
            JROT(s00,s22,s02, s01,s12, v00,v02, v10,v12, v20,v22);
            JROT(s11,s22,s12, s01,s02, v01,v02, v11,v12, v21,v22);
        }
#undef JROT
        float v1x,v1y,v1z, v2x,v2y,v2z;
        if (s00 <= s11 && s00 <= s22) {
            v1x=v01; v1y=v11; v1z=v21;  v2x=v02; v2y=v12; v2z=v22;
        } else if (s11 <= s22) {
            v1x=v02; v1y=v12; v1z=v22;  v2x=v00; v2y=v10; v2z=v20;
        } else {
            v1x=v00; v1y=v10; v1z=v20;  v2x=v01; v2y=v11; v2z=v21;
        }
        float u1x = p00*v1x + p01*v1y + p02*v1z;
        float u1y = p10*v1x + p11*v1y + p12*v1z;
        float u1z = p20*v1x + p21*v1y + p22*v1z;
        float inv = 1.0f / sqrtf(u1x*u1x + u1y*u1y + u1z*u1z);
        u1x*=inv; u1y*=inv; u1z*=inv;
        float u2x = p00*v2x + p01*v2y + p02*v2z;
        float u2y = p10*v2x + p11*v2y + p12*v2z;
        float u2z = p20*v2x + p21*v2y + p22*v2z;
        float d = u2x*u1x + u2y*u1y + u2z*u1z;   // Gram-Schmidt
        u2x -= d*u1x; u2y -= d*u1y; u2z -= d*u1z;
        inv = 1.0f / sqrtf(u2x*u2x + u2y*u2y + u2z*u2z);
        u2x*=inv; u2y*=inv; u2z*=inv;
        float u3x = u1y*u2z - u1z*u2y;
        float u3y = u1z*u2x - u1x*u2z;
        float u3z = u1x*u2y - u1y*u2x;
        float v3x = v1y*v2z - v1z*v2y;
        float v3y = v1z*v2x - v1x*v2z;
        float v3z = v1x*v2y - v1y*v2x;
        w[0] = u1x*v1x + u2x*v2x + u3x*v3x;
        w[1] = u1x*v1y + u2x*v2y + u3x*v3y;
        w[2] = u1x*v1z + u2x*v2z + u3x*v3z;
        w[3] = u1y*v1x + u2y*v2x + u3y*v3x;
        w[4] = u1y*v1y + u2y*v2y + u3y*v3y;
        w[5] = u1y*v1z + u2y*v2z + u3y*v3z;
        w[6] = u1z*v1x + u2z*v2x + u3z*v3x;
        w[7] = u1z*v1y + u2z*v2y + u3z*v3y;
        w[8] = u1z*v1z + u2z*v2z + u3z*v3z;
        // w[9..11] (xc) unchanged
    }
    __syncthreads();

    // ---- 4. apply (wave-per-batch, 2 sequential); store DIRECTLY to global ----
    int n0 = nn_idx[lane];
    int n1 = nn_idx[lane + 64];
    #pragma unroll
    for (int s = 0; s < 2; ++s) {
        int lb = 2*wid + s;
        const float* row = rowbuf[lb];
        const float* w = pbuf[lb];   // broadcast reads (uniform address)
        float r00=w[0], r01=w[1], r02=w[2];
        float r10=w[3], r11=w[4], r12=w[5];
        float r20=w[6], r21=w[7], r22=w[8];
        float xc0=w[9], xc1=w[10], xc2=w[11];
        float a0 = row[n0*3+0] - xc0;
        float a1 = row[n0*3+1] - xc1;
        float a2 = row[n0*3+2] - xc2;
        float b0 = row[n1*3+0] - xc0;
        float b1 = row[n1*3+1] - xc1;
        float b2 = row[n1*3+2] - xc2;
        float* dst = out + (bbase + lb) * SLOT_F;
        // per-lane 12 B at 3*lane / 3*(lane+64): contiguous across lanes -> full lines
        dst[3*lane+0] = a0*r00 + a1*r10 + a2*r20;
        dst[3*lane+1] = a0*r01 + a1*r11 + a2*r21;
        dst[3*lane+2] = a0*r02 + a1*r12 + a2*r22;
        dst[3*(lane+64)+0] = b0*r00 + b1*r10 + b2*r20;
        dst[3*(lane+64)+1] = b0*r01 + b1*r11 + b2*r21;
        dst[3*(lane+64)+2] = b0*r02 + b1*r12 + b2*r22;
    }
}

extern "C" void kernel_launch(void* const* d_in, const int* in_sizes, int n_in,
                              void* d_out, int out_size, void* d_ws, size_t ws_size,
                              hipStream_t stream) {
    // Assign inputs by element count (all four are distinct) — robust to ordering.
    const unsigned short* traj = (const unsigned short*)d_in[0];
    const unsigned short* refp = (const unsigned short*)d_in[1];
    const int* align_idx = (const int*)d_in[2];
    const int* nn_idx    = (const int*)d_in[3];
    for (int i = 0; i < n_in; ++i) {
        if      (in_sizes[i] == TRAJ_SZ) traj      = (const unsigned short*)d_in[i];
        else if (in_sizes[i] == REF_SZ)  refp      = (const unsigned short*)d_in[i];
        else if (in_sizes[i] == NA)      align_idx = (const int*)d_in[i];
        else if (in_sizes[i] == NM)      nn_idx    = (const int*)d_in[i];
    }
    float* out = (float*)d_out;

    k_fused<<<NB/NBB, 256, 0, stream>>>(traj, refp, align_idx, nn_idx, out);
}